// Round 4
// baseline (533.364 us; speedup 1.0000x reference)
//
#include <hip/hip_runtime.h>
#include <math.h>

#define BB   4
#define HH   96
#define WW   96
#define HW   (HH * WW)          // 9216
#define CIN  64
#define COUT 64
#define C2P  132                // concat channels 130 padded to 132
#define NROW (BB * HW)          // 36864
#define ZROW NROW               // extra all-zero row for invalid conv taps
#define NBLK (NROW / 64)        // 576 position-blocks for conv & deform
#define BPX  (NBLK / 8)         // 72 blocks per XCD in the swizzle

typedef float f4 __attribute__((ext_vector_type(4)));

__device__ __forceinline__ f4 fma4s(float s, f4 w, f4 a) {
    a.x = fmaf(s, w.x, a.x);
    a.y = fmaf(s, w.y, a.y);
    a.z = fmaf(s, w.z, a.z);
    a.w = fmaf(s, w.w, a.w);
    return a;
}

// ---------------------------------------------------------------------------
// Pre-pass 1: Xt[b*HW + hw][132] = concat(fi[64], fj[64], flow[2], 0, 0).
// Row ZROW (=NROW) is all zeros (conv border taps redirect here).
// ---------------------------------------------------------------------------
__global__ __launch_bounds__(256) void transpose_x_kernel(
    const float* __restrict__ fi, const float* __restrict__ fj,
    const float* __restrict__ fl, float* __restrict__ xt)
{
    int r = blockIdx.x * 256 + threadIdx.x;
    if (r > NROW) return;
    float* dst = xt + (size_t)r * C2P;
    if (r == NROW) {
        for (int c = 0; c < C2P; ++c) dst[c] = 0.0f;
        return;
    }
    int b = r / HW, hw = r % HW;
    const float* pi = fi + (size_t)b * CIN * HW + hw;
    const float* pj = fj + (size_t)b * CIN * HW + hw;
    const float* pf = fl + (size_t)b * 2 * HW + hw;
    f4 v;
#pragma unroll 4
    for (int cq = 0; cq < 16; ++cq) {
        v.x = pi[(size_t)(4 * cq + 0) * HW];
        v.y = pi[(size_t)(4 * cq + 1) * HW];
        v.z = pi[(size_t)(4 * cq + 2) * HW];
        v.w = pi[(size_t)(4 * cq + 3) * HW];
        *(f4*)(dst + 4 * cq) = v;
    }
#pragma unroll 4
    for (int cq = 0; cq < 16; ++cq) {
        v.x = pj[(size_t)(4 * cq + 0) * HW];
        v.y = pj[(size_t)(4 * cq + 1) * HW];
        v.z = pj[(size_t)(4 * cq + 2) * HW];
        v.w = pj[(size_t)(4 * cq + 3) * HW];
        *(f4*)(dst + 64 + 4 * cq) = v;
    }
    v.x = pf[0];
    v.y = pf[HW];
    v.z = 0.0f;
    v.w = 0.0f;
    *(f4*)(dst + 128) = v;
}

// ---------------------------------------------------------------------------
// Pre-pass 2: weight transposes.
// Wa[(t*132 + c)*28 + oc]: oc 0..17 offset, 18..26 modulator, 27 dummy(0);
//   c >= 130 zero pad.
// Wb[(k*64 + c)*64 + o] = w_reg[o][c][k]
// ---------------------------------------------------------------------------
__global__ __launch_bounds__(256) void transpose_w_kernel(
    const float* __restrict__ w_off, const float* __restrict__ w_mod,
    const float* __restrict__ w_reg, float* __restrict__ wa,
    float* __restrict__ wb)
{
    int e = blockIdx.x * 256 + threadIdx.x;
    const int NA = 9 * 132 * 28;
    if (e < NA) {
        int oc = e % 28;
        int c = (e / 28) % 132;
        int t = e / (28 * 132);
        float v = 0.0f;
        if (oc < 27 && c < 130) {
            if (oc < 18) v = w_off[((size_t)oc * 130 + c) * 9 + t];
            else         v = w_mod[((size_t)(oc - 18) * 130 + c) * 9 + t];
        }
        wa[e] = v;
    } else {
        int e2 = e - NA;
        if (e2 < 9 * 64 * 64) {
            int o = e2 % 64;
            int c = (e2 / 64) % 64;
            int k = e2 / 4096;
            wb[e2] = w_reg[((size_t)o * 64 + c) * 9 + k];
        }
    }
}

// ---------------------------------------------------------------------------
// Kernel A: offset+modulator 3x3 convs, LDS-shared patch rows.
// Block = 256 threads = 64 positions x 4 groups; group q computes combined
// output channels q*7 .. q*7+6 (27 real + 1 dummy). Per tap t the block
// stages the 64 needed Xt rows (132 ch) in LDS once.
// ---------------------------------------------------------------------------
__global__ __launch_bounds__(256) void conv_offmod_kernel(
    const float* __restrict__ xt, const float* __restrict__ wa,
    const float* __restrict__ b_off, const float* __restrict__ b_mod,
    float* __restrict__ off_out, float* __restrict__ mod_out)
{
    __shared__ f4 xrow[33 * 64];            // [cq][p], 33.8 KB

    int p = threadIdx.x & 63;
    int q = threadIdx.x >> 6;               // 0..3, wave-uniform
    int lb = (blockIdx.x & 7) * BPX + (blockIdx.x >> 3);  // XCD-contiguous
    int gpos = lb * 64 + p;
    int b = gpos / HW;                      // wave-uniform (HW % 64 == 0)
    int hw = gpos - b * HW;
    int x = hw % WW, y = hw / WW;
    int oc0 = q * 7;

    float acc[7];
#pragma unroll
    for (int j = 0; j < 7; ++j) {
        int oc = oc0 + j;
        acc[j] = (oc < 18) ? b_off[oc] : (oc < 27 ? b_mod[oc - 18] : 0.0f);
    }

#pragma unroll
    for (int t = 0; t < 9; ++t) {
        int yy = y + t / 3 - 1;
        int xx = x + t % 3 - 1;
        bool ok = (yy >= 0) && (yy < HH) && (xx >= 0) && (xx < WW);
        int r = ok ? (b * HW + yy * WW + xx) : ZROW;
        const f4* src = (const f4*)(xt + (size_t)r * C2P);
#pragma unroll
        for (int i = 0; i < 9; ++i) {
            int cq = q + 4 * i;
            if (cq < 33) xrow[cq * 64 + p] = src[cq];
        }
        __syncthreads();

        const float* wt = wa + (size_t)t * 132 * 28 + oc0;
#pragma unroll 3
        for (int cq = 0; cq < 33; ++cq) {
            f4 xv = xrow[cq * 64 + p];
#pragma unroll
            for (int cc = 0; cc < 4; ++cc) {
                float xs = (cc == 0) ? xv.x : (cc == 1) ? xv.y
                         : (cc == 2) ? xv.z : xv.w;
                const float* wr = wt + (size_t)(4 * cq + cc) * 28;
#pragma unroll
                for (int j = 0; j < 7; ++j)
                    acc[j] = fmaf(xs, wr[j], acc[j]);
            }
        }
        __syncthreads();
    }

#pragma unroll
    for (int j = 0; j < 7; ++j) {
        int oc = oc0 + j;
        if (oc < 18)
            off_out[((size_t)(b * 18 + oc)) * HW + hw] = acc[j];
        else if (oc < 27)
            mod_out[((size_t)(b * 9 + (oc - 18))) * HW + hw] =
                2.0f / (1.0f + expf(-acc[j]));
    }
}

// ---------------------------------------------------------------------------
// Kernel B: modulated deformable conv, LDS-shared gathers.
// Block = 256 threads = 64 positions x 4 og-groups; og computes outputs
// og*16 .. og*16+15. Per tap k the block cooperatively gathers + bilinear-
// combines val[c][p] for 64 channels into LDS once (og handles cq og*4..+3),
// then all groups contract against wave-uniform weights.
// ---------------------------------------------------------------------------
__global__ __launch_bounds__(256) void deform_kernel(
    const float* __restrict__ xt, const float* __restrict__ wb,
    const float* __restrict__ off_in, const float* __restrict__ mod_in,
    float* __restrict__ out)
{
    __shared__ f4 val[16 * 64];             // [cq][p], 16 KB

    int p  = threadIdx.x & 63;
    int og = threadIdx.x >> 6;              // 0..3, wave-uniform
    int lb = (blockIdx.x & 7) * BPX + (blockIdx.x >> 3); // XCD-contiguous
    int gpos = lb * 64 + p;
    int b = gpos / HW;                      // wave-uniform
    int hw = gpos - b * HW;
    int x = hw % WW, y = hw / WW;

    const float* offp = off_in + (size_t)b * 18 * HW + hw;
    const float* modp = mod_in + (size_t)b * 9 * HW + hw;

    f4 acc0 = {0.f, 0.f, 0.f, 0.f};
    f4 acc1 = acc0, acc2 = acc0, acc3 = acc0;

    for (int k = 0; k < 9; ++k) {
        int ky = k / 3, kx = k - 3 * ky;
        float dy = offp[(size_t)(2 * k) * HW];
        float dx = offp[(size_t)(2 * k + 1) * HW];
        float m  = modp[(size_t)k * HW];

        float py = (float)(y - 1 + ky) + dy;
        float px = (float)(x - 1 + kx) + dx;
        float fy = floorf(py), fx = floorf(px);
        int   y0 = (int)fy,    x0 = (int)fx;
        float wy = py - fy,    wx = px - fx;
        int   y1 = y0 + 1,     x1 = x0 + 1;

        bool y0v = (y0 >= 0) && (y0 < HH);
        bool y1v = (y1 >= 0) && (y1 < HH);
        bool x0v = (x0 >= 0) && (x0 < WW);
        bool x1v = (x1 >= 0) && (x1 < WW);

        float w00 = (1.f - wy) * (1.f - wx) * ((y0v && x0v) ? m : 0.f);
        float w01 = (1.f - wy) * wx         * ((y0v && x1v) ? m : 0.f);
        float w10 = wy * (1.f - wx)         * ((y1v && x0v) ? m : 0.f);
        float w11 = wy * wx                 * ((y1v && x1v) ? m : 0.f);

        int y0c = min(max(y0, 0), HH - 1), y1c = min(max(y1, 0), HH - 1);
        int x0c = min(max(x0, 0), WW - 1), x1c = min(max(x1, 0), WW - 1);
        int rb = b * HW;
        const float* b00 = xt + (size_t)(rb + y0c * WW + x0c) * C2P + 64 + og * 16;
        const float* b01 = xt + (size_t)(rb + y0c * WW + x1c) * C2P + 64 + og * 16;
        const float* b10 = xt + (size_t)(rb + y1c * WW + x0c) * C2P + 64 + og * 16;
        const float* b11 = xt + (size_t)(rb + y1c * WW + x1c) * C2P + 64 + og * 16;

        // gather + bilinear for my 4 channel-quads -> LDS
#pragma unroll
        for (int i = 0; i < 4; ++i) {
            f4 a00 = *(const f4*)(b00 + 4 * i);
            f4 a01 = *(const f4*)(b01 + 4 * i);
            f4 a10 = *(const f4*)(b10 + 4 * i);
            f4 a11 = *(const f4*)(b11 + 4 * i);
            f4 v;
            v.x = fmaf(w11, a11.x, fmaf(w10, a10.x, fmaf(w01, a01.x, w00 * a00.x)));
            v.y = fmaf(w11, a11.y, fmaf(w10, a10.y, fmaf(w01, a01.y, w00 * a00.y)));
            v.z = fmaf(w11, a11.z, fmaf(w10, a10.z, fmaf(w01, a01.z, w00 * a00.z)));
            v.w = fmaf(w11, a11.w, fmaf(w10, a10.w, fmaf(w01, a01.w, w00 * a00.w)));
            val[(og * 4 + i) * 64 + p] = v;
        }
        __syncthreads();

        // contract 64 channels against my 16 output columns
        const float* wk = wb + (size_t)k * 4096 + og * 16;
#pragma unroll 2
        for (int cq = 0; cq < 16; ++cq) {
            f4 v = val[cq * 64 + p];
#pragma unroll
            for (int cc = 0; cc < 4; ++cc) {
                float vs = (cc == 0) ? v.x : (cc == 1) ? v.y
                         : (cc == 2) ? v.z : v.w;
                const f4* wv = (const f4*)(wk + (size_t)(4 * cq + cc) * 64);
                acc0 = fma4s(vs, wv[0], acc0);
                acc1 = fma4s(vs, wv[1], acc1);
                acc2 = fma4s(vs, wv[2], acc2);
                acc3 = fma4s(vs, wv[3], acc3);
            }
        }
        __syncthreads();
    }

    float* op = out + ((size_t)(b * COUT + og * 16)) * HW + hw;
    op[(size_t)0  * HW] = acc0.x;  op[(size_t)1  * HW] = acc0.y;
    op[(size_t)2  * HW] = acc0.z;  op[(size_t)3  * HW] = acc0.w;
    op[(size_t)4  * HW] = acc1.x;  op[(size_t)5  * HW] = acc1.y;
    op[(size_t)6  * HW] = acc1.z;  op[(size_t)7  * HW] = acc1.w;
    op[(size_t)8  * HW] = acc2.x;  op[(size_t)9  * HW] = acc2.y;
    op[(size_t)10 * HW] = acc2.z;  op[(size_t)11 * HW] = acc2.w;
    op[(size_t)12 * HW] = acc3.x;  op[(size_t)13 * HW] = acc3.y;
    op[(size_t)14 * HW] = acc3.z;  op[(size_t)15 * HW] = acc3.w;
}

extern "C" void kernel_launch(void* const* d_in, const int* in_sizes, int n_in,
                              void* d_out, int out_size, void* d_ws, size_t ws_size,
                              hipStream_t stream)
{
    const float* frame_i = (const float*)d_in[0];
    const float* frame_j = (const float*)d_in[1];
    const float* flow_ij = (const float*)d_in[2];
    const float* w_off   = (const float*)d_in[3];
    const float* b_off   = (const float*)d_in[4];
    const float* w_mod   = (const float*)d_in[5];
    const float* b_mod   = (const float*)d_in[6];
    const float* w_reg   = (const float*)d_in[7];
    float* out = (float*)d_out;

    // workspace layout (floats): Xt | Wa | Wb | off | mod  (~23.7 MB total)
    float* xt  = (float*)d_ws;
    float* wa  = xt  + (size_t)(NROW + 1) * C2P;      // 4,866,180
    float* wb  = wa  + 9 * 132 * 28;                  // 33,264
    float* off = wb  + 9 * 64 * 64;                   // 36,864
    float* mod = off + (size_t)BB * 18 * HW;          // 663,552

    {   // transposes
        int rows = NROW + 1;
        transpose_x_kernel<<<(rows + 255) / 256, 256, 0, stream>>>(
            frame_i, frame_j, flow_ij, xt);
        int wtotal = 9 * 132 * 28 + 9 * 64 * 64;
        transpose_w_kernel<<<(wtotal + 255) / 256, 256, 0, stream>>>(
            w_off, w_mod, w_reg, wa, wb);
    }

    {   // conv: NBLK=576 blocks x 256 threads (64 positions each)
        conv_offmod_kernel<<<NBLK, 256, 0, stream>>>(
            xt, wa, b_off, b_mod, off, mod);
    }

    {   // deform: NBLK=576 blocks x 256 threads (64 positions each)
        deform_kernel<<<NBLK, 256, 0, stream>>>(
            xt, wb, off, mod, out);
    }
}

// Round 5
// 274.633 us; speedup vs baseline: 1.9421x; 1.9421x over previous
//
#include <hip/hip_runtime.h>
#include <math.h>

#define BB   4
#define HH   96
#define WW   96
#define HW   (HH * WW)          // 9216
#define CIN  64
#define COUT 64
#define C2P  132                // concat channels 130 padded to 132
#define NROW (BB * HW)          // 36864
#define ZROW NROW               // extra all-zero row for invalid conv taps
#define NSTRIP (NROW / 64)      // 576 position-strips (64 positions each)
#define BPX  (NSTRIP / 8)       // 72 strips per XCD in the swizzle

typedef float f4 __attribute__((ext_vector_type(4)));

__device__ __forceinline__ f4 fma4s(float s, f4 w, f4 a) {
    a.x = fmaf(s, w.x, a.x);
    a.y = fmaf(s, w.y, a.y);
    a.z = fmaf(s, w.z, a.z);
    a.w = fmaf(s, w.w, a.w);
    return a;
}

// ---------------------------------------------------------------------------
// Pre-pass 1: Xt[b*HW + hw][132] = concat(fi[64], fj[64], flow[2], 0, 0).
// Row ZROW (=NROW) is all zeros (conv border taps redirect here).
// ---------------------------------------------------------------------------
__global__ __launch_bounds__(256) void transpose_x_kernel(
    const float* __restrict__ fi, const float* __restrict__ fj,
    const float* __restrict__ fl, float* __restrict__ xt)
{
    int r = blockIdx.x * 256 + threadIdx.x;
    if (r > NROW) return;
    float* dst = xt + (size_t)r * C2P;
    if (r == NROW) {
        for (int c = 0; c < C2P; ++c) dst[c] = 0.0f;
        return;
    }
    int b = r / HW, hw = r % HW;
    const float* pi = fi + (size_t)b * CIN * HW + hw;
    const float* pj = fj + (size_t)b * CIN * HW + hw;
    const float* pf = fl + (size_t)b * 2 * HW + hw;
    f4 v;
#pragma unroll 4
    for (int cq = 0; cq < 16; ++cq) {
        v.x = pi[(size_t)(4 * cq + 0) * HW];
        v.y = pi[(size_t)(4 * cq + 1) * HW];
        v.z = pi[(size_t)(4 * cq + 2) * HW];
        v.w = pi[(size_t)(4 * cq + 3) * HW];
        *(f4*)(dst + 4 * cq) = v;
    }
#pragma unroll 4
    for (int cq = 0; cq < 16; ++cq) {
        v.x = pj[(size_t)(4 * cq + 0) * HW];
        v.y = pj[(size_t)(4 * cq + 1) * HW];
        v.z = pj[(size_t)(4 * cq + 2) * HW];
        v.w = pj[(size_t)(4 * cq + 3) * HW];
        *(f4*)(dst + 64 + 4 * cq) = v;
    }
    v.x = pf[0];
    v.y = pf[HW];
    v.z = 0.0f;
    v.w = 0.0f;
    *(f4*)(dst + 128) = v;
}

// ---------------------------------------------------------------------------
// Pre-pass 2: weight transposes.
// Wa[(t*132 + c)*28 + oc]: oc 0..17 offset, 18..26 modulator, 27 dummy(0);
//   c >= 130 zero pad.
// Wb[(k*64 + c)*64 + o] = w_reg[o][c][k]
// ---------------------------------------------------------------------------
__global__ __launch_bounds__(256) void transpose_w_kernel(
    const float* __restrict__ w_off, const float* __restrict__ w_mod,
    const float* __restrict__ w_reg, float* __restrict__ wa,
    float* __restrict__ wb)
{
    int e = blockIdx.x * 256 + threadIdx.x;
    const int NA = 9 * 132 * 28;
    if (e < NA) {
        int oc = e % 28;
        int c = (e / 28) % 132;
        int t = e / (28 * 132);
        float v = 0.0f;
        if (oc < 27 && c < 130) {
            if (oc < 18) v = w_off[((size_t)oc * 130 + c) * 9 + t];
            else         v = w_mod[((size_t)(oc - 18) * 130 + c) * 9 + t];
        }
        wa[e] = v;
    } else {
        int e2 = e - NA;
        if (e2 < 9 * 64 * 64) {
            int o = e2 % 64;
            int c = (e2 / 64) % 64;
            int k = e2 / 4096;
            wb[e2] = w_reg[((size_t)o * 64 + c) * 9 + k];
        }
    }
}

// ---------------------------------------------------------------------------
// Kernel A: offset+modulator convs, K-split 2-way (taps 0-4 / 5-8).
// Grid 1152: u = bid>>1 selects the position strip (XCD-swizzled), half =
// bid&1 selects the tap range. Block = 64 positions x 4 groups of 7 combined
// output channels. Partial sums atomicAdd into raw[28][NROW] (pre-zeroed).
// Weights wave-uniform (readfirstlane q) -> scalar loads.
// ---------------------------------------------------------------------------
__global__ __launch_bounds__(256) void conv_offmod_kernel(
    const float* __restrict__ xt, const float* __restrict__ wa,
    float* __restrict__ raw)
{
    __shared__ f4 xrow[33 * 64];            // [cq][p], 33.8 KB

    int p = threadIdx.x & 63;
    int q = __builtin_amdgcn_readfirstlane(threadIdx.x >> 6);  // 0..3
    int u    = blockIdx.x >> 1;             // 0..575 position strip
    int half = blockIdx.x & 1;
    int lb = (u & 7) * BPX + (u >> 3);      // XCD-contiguous
    int gpos = lb * 64 + p;
    int b = gpos / HW;                      // wave-uniform (HW % 64 == 0)
    int hw = gpos - b * HW;
    int x = hw % WW, y = hw / WW;
    int oc0 = q * 7;
    int t0 = half ? 5 : 0;
    int t1 = half ? 9 : 5;

    float acc[7] = {0.f, 0.f, 0.f, 0.f, 0.f, 0.f, 0.f};

    for (int t = t0; t < t1; ++t) {
        int yy = y + t / 3 - 1;
        int xx = x + t % 3 - 1;
        bool ok = (yy >= 0) && (yy < HH) && (xx >= 0) && (xx < WW);
        int r = ok ? (b * HW + yy * WW + xx) : ZROW;
        const f4* src = (const f4*)(xt + (size_t)r * C2P);
#pragma unroll
        for (int i = 0; i < 9; ++i) {
            int cq = q + 4 * i;
            if (cq < 33) xrow[cq * 64 + p] = src[cq];
        }
        __syncthreads();

        const float* wt = wa + (size_t)t * 132 * 28 + oc0;
#pragma unroll 3
        for (int cq = 0; cq < 33; ++cq) {
            f4 xv = xrow[cq * 64 + p];
#pragma unroll
            for (int cc = 0; cc < 4; ++cc) {
                float xs = (cc == 0) ? xv.x : (cc == 1) ? xv.y
                         : (cc == 2) ? xv.z : xv.w;
                const float* wr = wt + (size_t)(4 * cq + cc) * 28;
#pragma unroll
                for (int j = 0; j < 7; ++j)
                    acc[j] = fmaf(xs, wr[j], acc[j]);
            }
        }
        __syncthreads();
    }

#pragma unroll
    for (int j = 0; j < 7; ++j)             // oc==27 pad row is harmless
        atomicAdd(raw + (size_t)(oc0 + j) * NROW + gpos, acc[j]);
}

// ---------------------------------------------------------------------------
// Conv reduce: in-place bias + sigmoid over raw[27][NROW].
// raw[0..17] -> offset (+bias); raw[18..26] -> 2*sigmoid(x + bias).
// ---------------------------------------------------------------------------
__global__ __launch_bounds__(256) void conv_reduce_kernel(
    float* __restrict__ raw, const float* __restrict__ b_off,
    const float* __restrict__ b_mod)
{
    int e = blockIdx.x * 256 + threadIdx.x;
    if (e >= 27 * NROW) return;
    int oc = e / NROW;
    float v = raw[e];
    if (oc < 18) raw[e] = v + b_off[oc];
    else         raw[e] = 2.0f / (1.0f + expf(-(v + b_mod[oc - 18])));
}

// ---------------------------------------------------------------------------
// Kernel B: modulated deformable conv, K-split 2-way (taps 0-4 / 5-8).
// Grid 1152 as kernel A. Block = 64 positions x 4 og-groups of 16 outputs.
// Per tap: cooperative bilinear gather of 64 channels into LDS (og handles
// channel-quads og*4..og*4+3), then contract vs wave-uniform scalar weights.
// Partial sums atomicAdd into pre-zeroed d_out.
// ---------------------------------------------------------------------------
__global__ __launch_bounds__(256) void deform_kernel(
    const float* __restrict__ xt, const float* __restrict__ wb,
    const float* __restrict__ raw, float* __restrict__ out)
{
    __shared__ f4 val[16 * 64];             // [cq][p], 16 KB

    int p  = threadIdx.x & 63;
    int og = __builtin_amdgcn_readfirstlane(threadIdx.x >> 6);  // 0..3
    int u    = blockIdx.x >> 1;
    int half = blockIdx.x & 1;
    int lb = (u & 7) * BPX + (u >> 3);      // XCD-contiguous
    int gpos = lb * 64 + p;
    int b = gpos / HW;                      // wave-uniform
    int hw = gpos - b * HW;
    int x = hw % WW, y = hw / WW;
    int k0 = half ? 5 : 0;
    int k1 = half ? 9 : 5;

    const float* offp = raw + gpos;         // ch c at raw[c*NROW + gpos]

    f4 acc0 = {0.f, 0.f, 0.f, 0.f};
    f4 acc1 = acc0, acc2 = acc0, acc3 = acc0;

    for (int k = k0; k < k1; ++k) {
        int ky = k / 3, kx = k - 3 * ky;
        float dy = offp[(size_t)(2 * k) * NROW];
        float dx = offp[(size_t)(2 * k + 1) * NROW];
        float m  = offp[(size_t)(18 + k) * NROW];

        float py = (float)(y - 1 + ky) + dy;
        float px = (float)(x - 1 + kx) + dx;
        float fy = floorf(py), fx = floorf(px);
        int   y0 = (int)fy,    x0 = (int)fx;
        float wy = py - fy,    wx = px - fx;
        int   y1 = y0 + 1,     x1 = x0 + 1;

        bool y0v = (y0 >= 0) && (y0 < HH);
        bool y1v = (y1 >= 0) && (y1 < HH);
        bool x0v = (x0 >= 0) && (x0 < WW);
        bool x1v = (x1 >= 0) && (x1 < WW);

        float w00 = (1.f - wy) * (1.f - wx) * ((y0v && x0v) ? m : 0.f);
        float w01 = (1.f - wy) * wx         * ((y0v && x1v) ? m : 0.f);
        float w10 = wy * (1.f - wx)         * ((y1v && x0v) ? m : 0.f);
        float w11 = wy * wx                 * ((y1v && x1v) ? m : 0.f);

        int y0c = min(max(y0, 0), HH - 1), y1c = min(max(y1, 0), HH - 1);
        int x0c = min(max(x0, 0), WW - 1), x1c = min(max(x1, 0), WW - 1);
        int rb = b * HW;
        const float* b00 = xt + (size_t)(rb + y0c * WW + x0c) * C2P + 64 + og * 16;
        const float* b01 = xt + (size_t)(rb + y0c * WW + x1c) * C2P + 64 + og * 16;
        const float* b10 = xt + (size_t)(rb + y1c * WW + x0c) * C2P + 64 + og * 16;
        const float* b11 = xt + (size_t)(rb + y1c * WW + x1c) * C2P + 64 + og * 16;

#pragma unroll
        for (int i = 0; i < 4; ++i) {
            f4 a00 = *(const f4*)(b00 + 4 * i);
            f4 a01 = *(const f4*)(b01 + 4 * i);
            f4 a10 = *(const f4*)(b10 + 4 * i);
            f4 a11 = *(const f4*)(b11 + 4 * i);
            f4 v;
            v.x = fmaf(w11, a11.x, fmaf(w10, a10.x, fmaf(w01, a01.x, w00 * a00.x)));
            v.y = fmaf(w11, a11.y, fmaf(w10, a10.y, fmaf(w01, a01.y, w00 * a00.y)));
            v.z = fmaf(w11, a11.z, fmaf(w10, a10.z, fmaf(w01, a01.z, w00 * a00.z)));
            v.w = fmaf(w11, a11.w, fmaf(w10, a10.w, fmaf(w01, a01.w, w00 * a00.w)));
            val[(og * 4 + i) * 64 + p] = v;
        }
        __syncthreads();

        const float* wk = wb + (size_t)k * 4096 + og * 16;
#pragma unroll 2
        for (int cq = 0; cq < 16; ++cq) {
            f4 v = val[cq * 64 + p];
#pragma unroll
            for (int cc = 0; cc < 4; ++cc) {
                float vs = (cc == 0) ? v.x : (cc == 1) ? v.y
                         : (cc == 2) ? v.z : v.w;
                const f4* wv = (const f4*)(wk + (size_t)(4 * cq + cc) * 64);
                acc0 = fma4s(vs, wv[0], acc0);
                acc1 = fma4s(vs, wv[1], acc1);
                acc2 = fma4s(vs, wv[2], acc2);
                acc3 = fma4s(vs, wv[3], acc3);
            }
        }
        __syncthreads();
    }

    float* op = out + ((size_t)(b * COUT + og * 16)) * HW + hw;
    atomicAdd(op + (size_t)0  * HW, acc0.x);
    atomicAdd(op + (size_t)1  * HW, acc0.y);
    atomicAdd(op + (size_t)2  * HW, acc0.z);
    atomicAdd(op + (size_t)3  * HW, acc0.w);
    atomicAdd(op + (size_t)4  * HW, acc1.x);
    atomicAdd(op + (size_t)5  * HW, acc1.y);
    atomicAdd(op + (size_t)6  * HW, acc1.z);
    atomicAdd(op + (size_t)7  * HW, acc1.w);
    atomicAdd(op + (size_t)8  * HW, acc2.x);
    atomicAdd(op + (size_t)9  * HW, acc2.y);
    atomicAdd(op + (size_t)10 * HW, acc2.z);
    atomicAdd(op + (size_t)11 * HW, acc2.w);
    atomicAdd(op + (size_t)12 * HW, acc3.x);
    atomicAdd(op + (size_t)13 * HW, acc3.y);
    atomicAdd(op + (size_t)14 * HW, acc3.z);
    atomicAdd(op + (size_t)15 * HW, acc3.w);
}

extern "C" void kernel_launch(void* const* d_in, const int* in_sizes, int n_in,
                              void* d_out, int out_size, void* d_ws, size_t ws_size,
                              hipStream_t stream)
{
    const float* frame_i = (const float*)d_in[0];
    const float* frame_j = (const float*)d_in[1];
    const float* flow_ij = (const float*)d_in[2];
    const float* w_off   = (const float*)d_in[3];
    const float* b_off   = (const float*)d_in[4];
    const float* w_mod   = (const float*)d_in[5];
    const float* b_mod   = (const float*)d_in[6];
    const float* w_reg   = (const float*)d_in[7];
    float* out = (float*)d_out;

    // workspace (floats): Xt | Wa | Wb | raw   (~23.9 MB)
    float* xt  = (float*)d_ws;
    float* wa  = xt  + (size_t)(NROW + 1) * C2P;      // 4,866,180
    float* wb  = wa  + 9 * 132 * 28;                  // 33,264
    float* raw = wb  + 9 * 64 * 64;                   // 36,864; raw: 28*NROW

    // zero accumulation targets (atomics add into them)
    hipMemsetAsync(raw, 0, (size_t)28 * NROW * sizeof(float), stream);
    hipMemsetAsync(out, 0, (size_t)out_size * sizeof(float), stream);

    {   // transposes
        int rows = NROW + 1;
        transpose_x_kernel<<<(rows + 255) / 256, 256, 0, stream>>>(
            frame_i, frame_j, flow_ij, xt);
        int wtotal = 9 * 132 * 28 + 9 * 64 * 64;
        transpose_w_kernel<<<(wtotal + 255) / 256, 256, 0, stream>>>(
            w_off, w_mod, w_reg, wa, wb);
    }

    {   // conv halves: 1152 blocks (576 strips x 2 tap-halves)
        conv_offmod_kernel<<<2 * NSTRIP, 256, 0, stream>>>(xt, wa, raw);
    }

    {   // bias + sigmoid in place
        int total = 27 * NROW;
        conv_reduce_kernel<<<(total + 255) / 256, 256, 0, stream>>>(
            raw, b_off, b_mod);
    }

    {   // deform halves: 1152 blocks
        deform_kernel<<<2 * NSTRIP, 256, 0, stream>>>(xt, wb, raw, out);
    }
}

// Round 6
// 146.950 us; speedup vs baseline: 3.6296x; 1.8689x over previous
//
#include <hip/hip_runtime.h>
#include <math.h>

#define BB   4
#define HH   96
#define WW   96
#define HW   (HH * WW)          // 9216
#define CIN  64
#define COUT 64
#define C2B  160                // bf16 concat channels padded 130 -> 160 (5 K-steps of 32)
#define NROW (BB * HW)          // 36864
#define ZROW NROW               // all-zero row for invalid conv taps
#define NSTRIP (NROW / 16)      // 2304 strips of 16 positions
#define SPX  (NSTRIP / 8)       // 288 strips per XCD

typedef short v8s __attribute__((ext_vector_type(8)));   // 8 bf16 = 4 VGPRs
typedef float v4f __attribute__((ext_vector_type(4)));

__device__ __forceinline__ unsigned short f2bf(float f) {
    unsigned u = __float_as_uint(f);
    return (unsigned short)((u + 0x7FFFu + ((u >> 16) & 1u)) >> 16);  // RTN-even
}
__device__ __forceinline__ unsigned pack2(float a, float b) {
    return (unsigned)f2bf(a) | ((unsigned)f2bf(b) << 16);
}
// bilinear-combine one packed-bf16-pair dword from each of 4 corners
__device__ __forceinline__ unsigned bil2(unsigned a, unsigned b, unsigned c,
                                         unsigned d, float w00, float w01,
                                         float w10, float w11) {
    float lo = w00 * __uint_as_float(a << 16) + w01 * __uint_as_float(b << 16)
             + w10 * __uint_as_float(c << 16) + w11 * __uint_as_float(d << 16);
    float hi = w00 * __uint_as_float(a & 0xffff0000u)
             + w01 * __uint_as_float(b & 0xffff0000u)
             + w10 * __uint_as_float(c & 0xffff0000u)
             + w11 * __uint_as_float(d & 0xffff0000u);
    return pack2(lo, hi);
}

// ---------------------------------------------------------------------------
// Pre-pass 1: Xt[row][160] bf16 = concat(fi[64], fj[64], flow[2], 0-pad[30]).
// Row ZROW is all zeros.
// ---------------------------------------------------------------------------
__global__ __launch_bounds__(256) void transpose_x_kernel(
    const float* __restrict__ fi, const float* __restrict__ fj,
    const float* __restrict__ fl, unsigned short* __restrict__ xt)
{
    int r = blockIdx.x * 256 + threadIdx.x;
    if (r > NROW) return;
    unsigned* dst = (unsigned*)(xt + (size_t)r * C2B);   // 80 dwords per row
    if (r == NROW) {
        for (int i = 0; i < 80; ++i) dst[i] = 0u;
        return;
    }
    int b = r / HW, hw = r % HW;
    const float* pi = fi + (size_t)b * CIN * HW + hw;
    const float* pj = fj + (size_t)b * CIN * HW + hw;
    const float* pf = fl + (size_t)b * 2 * HW + hw;
#pragma unroll 8
    for (int cp = 0; cp < 32; ++cp)
        dst[cp] = pack2(pi[(size_t)(2 * cp) * HW], pi[(size_t)(2 * cp + 1) * HW]);
#pragma unroll 8
    for (int cp = 0; cp < 32; ++cp)
        dst[32 + cp] = pack2(pj[(size_t)(2 * cp) * HW], pj[(size_t)(2 * cp + 1) * HW]);
    dst[64] = pack2(pf[0], pf[HW]);
#pragma unroll
    for (int i = 65; i < 80; ++i) dst[i] = 0u;
}

// ---------------------------------------------------------------------------
// Pre-pass 2: weight transposes to bf16, MFMA-B-friendly layouts.
// Wa2[t][oc(32)][ch(160)]: oc 0..17 = w_off, 18..26 = w_mod, rest 0.
// Wb2[k][o(64)][ch(64)] = w_reg[o][c][k]
// ---------------------------------------------------------------------------
__global__ __launch_bounds__(256) void transpose_w_kernel(
    const float* __restrict__ w_off, const float* __restrict__ w_mod,
    const float* __restrict__ w_reg, unsigned short* __restrict__ wa2,
    unsigned short* __restrict__ wb2)
{
    int e = blockIdx.x * 256 + threadIdx.x;
    const int NA = 9 * 32 * C2B;            // 46080
    if (e < NA) {
        int c  = e % C2B;
        int oc = (e / C2B) % 32;
        int t  = e / (C2B * 32);
        float v = 0.0f;
        if (oc < 27 && c < 130) {
            if (oc < 18) v = w_off[((size_t)oc * 130 + c) * 9 + t];
            else         v = w_mod[((size_t)(oc - 18) * 130 + c) * 9 + t];
        }
        wa2[e] = f2bf(v);
    } else {
        int e2 = e - NA;
        if (e2 < 9 * 64 * 64) {
            int c = e2 % 64;
            int o = (e2 / 64) % 64;
            int k = e2 / 4096;
            wb2[e2] = f2bf(w_reg[((size_t)o * 64 + c) * 9 + k]);
        }
    }
}

// ---------------------------------------------------------------------------
// Kernel A: offset+modulator convs as implicit-GEMM MFMA.
// 1 wave/block, 16 positions (M) x 32 oc (N, two 16-tiles), K = 9 taps x 160.
// A loaded straight from global Xt rows (border taps -> ZROW); B from Wa2.
// Epilogue fuses bias + 2*sigmoid, stores raw[oc][pos] as dwordx4.
// ---------------------------------------------------------------------------
__global__ __launch_bounds__(64) void conv_mfma_kernel(
    const unsigned short* __restrict__ xt,
    const unsigned short* __restrict__ wa2,
    const float* __restrict__ b_off, const float* __restrict__ b_mod,
    float* __restrict__ raw)
{
    int l = threadIdx.x;
    int m = l & 15, g = l >> 4;
    int strip = (blockIdx.x & 7) * SPX + (blockIdx.x >> 3);   // XCD-contiguous
    int b = strip / (HW / 16);              // wave-uniform
    int hw0 = strip * 16 - b * HW;
    int hw = hw0 + m;
    int x = hw % WW, y = hw / WW;

    v4f acc0 = {0.f, 0.f, 0.f, 0.f};
    v4f acc1 = {0.f, 0.f, 0.f, 0.f};

    for (int t = 0; t < 9; ++t) {
        int ty = t / 3, tx = t - 3 * ty;
        int yy = y + ty - 1, xx = x + tx - 1;
        bool ok = ((unsigned)yy < HH) && ((unsigned)xx < WW);
        int row = ok ? (b * HW + yy * WW + xx) : ZROW;
        const unsigned short* ar = xt + (size_t)row * C2B + g * 8;
        const unsigned short* w0 = wa2 + ((size_t)(t * 32 + m)) * C2B + g * 8;
        const unsigned short* w1 = w0 + 16 * C2B;
#pragma unroll
        for (int ks = 0; ks < 5; ++ks) {
            v8s a  = *(const v8s*)(ar + ks * 32);
            v8s b0 = *(const v8s*)(w0 + ks * 32);
            v8s b1 = *(const v8s*)(w1 + ks * 32);
            acc0 = __builtin_amdgcn_mfma_f32_16x16x32_bf16(a, b0, acc0, 0, 0, 0);
            acc1 = __builtin_amdgcn_mfma_f32_16x16x32_bf16(a, b1, acc1, 0, 0, 0);
        }
    }

    // D: row = g*4+reg (position), col = m (oc within n-tile)
    int p0 = strip * 16 + g * 4;
    {   // n-tile 0: oc = m (0..15, all offset channels)
        float bo = b_off[m];
        v4f o0;
        o0.x = acc0.x + bo; o0.y = acc0.y + bo;
        o0.z = acc0.z + bo; o0.w = acc0.w + bo;
        *(v4f*)(raw + (size_t)m * NROW + p0) = o0;
    }
    int oc1 = 16 + m;
    if (oc1 < 27) {                          // n-tile 1: 16,17 offset; 18..26 mod
        v4f o1;
        if (oc1 < 18) {
            float bo = b_off[oc1];
            o1.x = acc1.x + bo; o1.y = acc1.y + bo;
            o1.z = acc1.z + bo; o1.w = acc1.w + bo;
        } else {
            float bm = b_mod[oc1 - 18];
            o1.x = 2.0f / (1.0f + expf(-(acc1.x + bm)));
            o1.y = 2.0f / (1.0f + expf(-(acc1.y + bm)));
            o1.z = 2.0f / (1.0f + expf(-(acc1.z + bm)));
            o1.w = 2.0f / (1.0f + expf(-(acc1.w + bm)));
        }
        *(v4f*)(raw + (size_t)oc1 * NROW + p0) = o1;
    }
}

// ---------------------------------------------------------------------------
// Kernel B: modulated deformable conv. 1 wave/block, 16 positions x 64 out.
// Per tap: wave bilinear-gathers 64 bf16 channels into LDS val[16][68]
// (lane l: pos l&15, channels (l>>4)*16..+15), then 2 K-steps x 4 N-tiles
// of mfma_f32_16x16x32_bf16. Direct dwordx4 stores (4 consecutive hw).
// ---------------------------------------------------------------------------
__global__ __launch_bounds__(64) void deform_mfma_kernel(
    const unsigned short* __restrict__ xt,
    const unsigned short* __restrict__ wb2,
    const float* __restrict__ raw, float* __restrict__ out)
{
    __shared__ __align__(16) unsigned short val[16 * 68];  // pad 64->68: 2-way max

    int l = threadIdx.x;
    int m = l & 15, g = l >> 4;
    int strip = (blockIdx.x & 7) * SPX + (blockIdx.x >> 3);
    int b = strip / (HW / 16);
    int hw0 = strip * 16 - b * HW;
    int hw = hw0 + m;
    int x = hw % WW, y = hw / WW;

    v4f acc[4];
#pragma unroll
    for (int nt = 0; nt < 4; ++nt) acc[nt] = (v4f){0.f, 0.f, 0.f, 0.f};

    for (int k = 0; k < 9; ++k) {
        int ky = k / 3, kx = k - 3 * ky;
        int pidx = strip * 16 + m;
        float dy = raw[(size_t)(2 * k) * NROW + pidx];
        float dx = raw[(size_t)(2 * k + 1) * NROW + pidx];
        float mm = raw[(size_t)(18 + k) * NROW + pidx];

        float py = (float)(y - 1 + ky) + dy;
        float px = (float)(x - 1 + kx) + dx;
        float fy = floorf(py), fx = floorf(px);
        int   y0 = (int)fy,    x0 = (int)fx;
        float wy = py - fy,    wx = px - fx;
        int   y1 = y0 + 1,     x1 = x0 + 1;

        bool y0v = (y0 >= 0) && (y0 < HH);
        bool y1v = (y1 >= 0) && (y1 < HH);
        bool x0v = (x0 >= 0) && (x0 < WW);
        bool x1v = (x1 >= 0) && (x1 < WW);

        float w00 = (1.f - wy) * (1.f - wx) * ((y0v && x0v) ? mm : 0.f);
        float w01 = (1.f - wy) * wx         * ((y0v && x1v) ? mm : 0.f);
        float w10 = wy * (1.f - wx)         * ((y1v && x0v) ? mm : 0.f);
        float w11 = wy * wx                 * ((y1v && x1v) ? mm : 0.f);

        int y0c = min(max(y0, 0), HH - 1), y1c = min(max(y1, 0), HH - 1);
        int x0c = min(max(x0, 0), WW - 1), x1c = min(max(x1, 0), WW - 1);
        int rb = b * HW;
        // fj channels live at +64 in the 160-ch row; my 16-ch chunk at +g*16
        const uint4* c00 = (const uint4*)(xt + (size_t)(rb + y0c * WW + x0c) * C2B + 64 + g * 16);
        const uint4* c01 = (const uint4*)(xt + (size_t)(rb + y0c * WW + x1c) * C2B + 64 + g * 16);
        const uint4* c10 = (const uint4*)(xt + (size_t)(rb + y1c * WW + x0c) * C2B + 64 + g * 16);
        const uint4* c11 = (const uint4*)(xt + (size_t)(rb + y1c * WW + x1c) * C2B + 64 + g * 16);

#pragma unroll
        for (int h = 0; h < 2; ++h) {
            uint4 u00 = c00[h], u01 = c01[h], u10 = c10[h], u11 = c11[h];
            uint4 ov;
            ov.x = bil2(u00.x, u01.x, u10.x, u11.x, w00, w01, w10, w11);
            ov.y = bil2(u00.y, u01.y, u10.y, u11.y, w00, w01, w10, w11);
            ov.z = bil2(u00.z, u01.z, u10.z, u11.z, w00, w01, w10, w11);
            ov.w = bil2(u00.w, u01.w, u10.w, u11.w, w00, w01, w10, w11);
            *(uint4*)(&val[m * 68 + g * 16 + h * 8]) = ov;
        }
        __syncthreads();   // single wave: lgkmcnt drain + cheap barrier

#pragma unroll
        for (int ks = 0; ks < 2; ++ks) {
            v8s a = *(const v8s*)(&val[m * 68 + ks * 32 + g * 8]);
            const unsigned short* wk = wb2 + (size_t)(k * 64 + m) * 64 + ks * 32 + g * 8;
#pragma unroll
            for (int nt = 0; nt < 4; ++nt) {
                v8s bb = *(const v8s*)(wk + nt * 16 * 64);
                acc[nt] = __builtin_amdgcn_mfma_f32_16x16x32_bf16(a, bb, acc[nt], 0, 0, 0);
            }
        }
        // no barrier needed before next tap's writes: single-wave program order
    }

    // D: row = g*4+reg (position), col = m; o = nt*16 + m
    float* op = out + ((size_t)(b * COUT + m)) * HW + hw0 + g * 4;
#pragma unroll
    for (int nt = 0; nt < 4; ++nt)
        *(v4f*)(op + (size_t)nt * 16 * HW) = acc[nt];
}

extern "C" void kernel_launch(void* const* d_in, const int* in_sizes, int n_in,
                              void* d_out, int out_size, void* d_ws, size_t ws_size,
                              hipStream_t stream)
{
    const float* frame_i = (const float*)d_in[0];
    const float* frame_j = (const float*)d_in[1];
    const float* flow_ij = (const float*)d_in[2];
    const float* w_off   = (const float*)d_in[3];
    const float* b_off   = (const float*)d_in[4];
    const float* w_mod   = (const float*)d_in[5];
    const float* b_mod   = (const float*)d_in[6];
    const float* w_reg   = (const float*)d_in[7];
    float* out = (float*)d_out;

    // workspace: raw fp32 [27][NROW] | Xt bf16 [NROW+1][160] | Wa2 | Wb2 (~16 MB)
    float*          raw = (float*)d_ws;
    unsigned short* xt  = (unsigned short*)(raw + (size_t)27 * NROW);
    unsigned short* wa2 = xt + (size_t)(NROW + 1) * C2B;
    unsigned short* wb2 = wa2 + 9 * 32 * C2B;

    {   // transposes
        int rows = NROW + 1;
        transpose_x_kernel<<<(rows + 255) / 256, 256, 0, stream>>>(
            frame_i, frame_j, flow_ij, xt);
        int wtotal = 9 * 32 * C2B + 9 * 64 * 64;
        transpose_w_kernel<<<(wtotal + 255) / 256, 256, 0, stream>>>(
            w_off, w_mod, w_reg, wa2, wb2);
    }

    conv_mfma_kernel<<<NSTRIP, 64, 0, stream>>>(xt, wa2, b_off, b_mod, raw);
    deform_mfma_kernel<<<NSTRIP, 64, 0, stream>>>(xt, wb2, raw, out);
}